// Round 14
// baseline (736.202 us; speedup 1.0000x reference)
//
#include <hip/hip_runtime.h>
#include <cstddef>
#include <cmath>
#include <type_traits>

#define BATCH 2
#define LSEQ 2048
#define DM 1024
#define DSTATE 16
#define DI 2048
#define DTR 64
#define XDR 96   // DTR + 2*DSTATE
#define NC 64    // scan chunks
#define TC 32    // timesteps per chunk (NC*TC == LSEQ)
#define PN (4096 * 96)  // per-z x_dbl partial size

static_assert(NC * TC == LSEQ, "chunking");
static_assert(TC == 32, "scan batching assumes TC==32 (4 batches of 8)");

using f32x4 = __attribute__((ext_vector_type(4))) float;
using bf16x8 = __attribute__((ext_vector_type(8))) short;

__device__ __forceinline__ unsigned short f2bf(float f) {
  union { float f; unsigned int u; } c; c.f = f;
  unsigned int u = c.u;
  return (unsigned short)((u + 0x7FFFu + ((u >> 16) & 1u)) >> 16);  // RNE
}
__device__ __forceinline__ float bf2f(unsigned short h) {
  union { unsigned int u; float f; } c; c.u = ((unsigned int)h) << 16;
  return c.f;
}
__device__ __forceinline__ unsigned int pack2(float a, float b) {
  return (unsigned int)f2bf(a) | ((unsigned int)f2bf(b) << 16);
}

__device__ __forceinline__ void gl_lds16(const void* g, void* l) {
  __builtin_amdgcn_global_load_lds(
      (const __attribute__((address_space(1))) void*)g,
      (__attribute__((address_space(3))) void*)l, 16, 0, 0);
}

__device__ __forceinline__ float softplus_fast(float x) {
  float ex = __expf(x);
  return (x > 20.f) ? x : __logf(1.f + ex);
}

// dA[n] = q^(n+1), binary-power tree (depth ~4 instead of 15-serial).
__device__ __forceinline__ void pow_tree(float q1, float* dA) {
  float q2 = q1 * q1;
  float q3 = q2 * q1;
  float q4 = q2 * q2;
  float q8 = q4 * q4;
  float q5 = q4 * q1, q6 = q4 * q2, q7 = q4 * q3;
  dA[0] = q1;  dA[1] = q2;  dA[2] = q3;  dA[3] = q4;
  dA[4] = q5;  dA[5] = q6;  dA[6] = q7;  dA[7] = q8;
  dA[8] = q8 * q1;  dA[9] = q8 * q2;  dA[10] = q8 * q3;  dA[11] = q8 * q4;
  dA[12] = q8 * q5; dA[13] = q8 * q6; dA[14] = q8 * q7;  dA[15] = q8 * q8;
}

// ---------------------------------------------------------------------------
// f32 -> bf16 conversion, 8 elems/thread (exact-size grids).
// ---------------------------------------------------------------------------
__global__ __launch_bounds__(256) void cvt_bf16_kernel(
    const float* __restrict__ s, unsigned short* __restrict__ d, int n8) {
  int i = blockIdx.x * 256 + threadIdx.x;
  if (i >= n8) return;
  const float4* sp = reinterpret_cast<const float4*>(s) + (size_t)i * 2;
  float4 a = sp[0], b = sp[1];
  uint4 v = make_uint4(pack2(a.x, a.y), pack2(a.z, a.w), pack2(b.x, b.y),
                       pack2(b.z, b.w));
  *(reinterpret_cast<uint4*>(d) + i) = v;
}

// ---------------------------------------------------------------------------
// NT GEMM, bf16 in, f32 or bf16 out.  BM=BN=128, BK=64, 4 waves (2x2).
// global_load_lds staging, pre-swizzled source slots + matching XOR on
// ds_read.  XCD-aware bijective block swizzle (requires nwg % 8 == 0).
// ---------------------------------------------------------------------------
template <typename OutT>
__global__ __launch_bounds__(256) void gemm_bf16_t(
    const unsigned short* __restrict__ A, const unsigned short* __restrict__ B,
    OutT* __restrict__ C, int K, int lda, int ldb, int ldc) {
  __shared__ __align__(16) unsigned short As[128][64];
  __shared__ __align__(16) unsigned short Bs[128][64];

  const int tid = threadIdx.x;
  const int lane = tid & 63;
  const int w = tid >> 6;

  const int gx = gridDim.x;
  const int nwg = gx * gridDim.y;
  const int id = blockIdx.y * gx + blockIdx.x;
  const int cpx = nwg >> 3;
  const int lt = (id & 7) * cpx + (id >> 3);
  const size_t m0 = (size_t)(lt / gx) * 128;
  const size_t n0 = (size_t)(lt % gx) * 128;

  const int rsub = lane >> 3;
  const int sslot = (lane & 7) ^ rsub;
  const unsigned short* Ab = A + m0 * lda + (size_t)rsub * lda + sslot * 8;
  const unsigned short* Bb = B + n0 * ldb + (size_t)rsub * ldb + sslot * 8;

  f32x4 acc[4][4] = {};

  const int fr = lane & 15;
  const int q = lane >> 4;
  const int f7 = fr & 7;

  for (int k0 = 0; k0 < K; k0 += 64) {
#pragma unroll
    for (int i = 0; i < 4; ++i) {
      const int r0 = w * 32 + i * 8;
      gl_lds16(Ab + (size_t)r0 * lda + k0, &As[r0][0]);
      gl_lds16(Bb + (size_t)r0 * ldb + k0, &Bs[r0][0]);
    }
    __syncthreads();

    bf16x8 af[4][2], bf_[4][2];
#pragma unroll
    for (int i = 0; i < 4; ++i) {
#pragma unroll
      for (int kk = 0; kk < 2; ++kk) {
        const int sA = (((kk * 4 + q) ^ f7) << 3);
        af[i][kk] = *reinterpret_cast<const bf16x8*>(
            &As[(w >> 1) * 64 + i * 16 + fr][sA]);
        bf_[i][kk] = *reinterpret_cast<const bf16x8*>(
            &Bs[(w & 1) * 64 + i * 16 + fr][sA]);
      }
    }
#pragma unroll
    for (int kk = 0; kk < 2; ++kk)
#pragma unroll
      for (int i = 0; i < 4; ++i)
#pragma unroll
        for (int j = 0; j < 4; ++j)
          acc[i][j] = __builtin_amdgcn_mfma_f32_16x16x32_bf16(
              af[i][kk], bf_[j][kk], acc[i][j], 0, 0, 0);
    __syncthreads();
  }

  const int crb = q * 4;
#pragma unroll
  for (int i = 0; i < 4; ++i) {
    size_t row = m0 + (w >> 1) * 64 + i * 16 + crb;
#pragma unroll
    for (int j = 0; j < 4; ++j) {
      size_t col = n0 + (w & 1) * 64 + j * 16 + fr;
#pragma unroll
      for (int r = 0; r < 4; ++r) {
        if constexpr (std::is_same_v<OutT, unsigned short>)
          C[(row + r) * ldc + col] = f2bf(acc[i][j][r]);
        else
          C[(row + r) * ldc + col] = acc[i][j][r];
      }
    }
  }
}

// ---------------------------------------------------------------------------
// Delta GEMM with fused bias+softplus epilogue, bf16 out.
// ---------------------------------------------------------------------------
__global__ __launch_bounds__(256) void gemm_delta(
    const unsigned short* __restrict__ A, const unsigned short* __restrict__ B,
    const float* __restrict__ bias, unsigned short* __restrict__ C, int K,
    int lda, int ldb, int ldc) {
  __shared__ __align__(16) unsigned short As[128][64];
  __shared__ __align__(16) unsigned short Bs[128][64];

  const int tid = threadIdx.x;
  const int lane = tid & 63;
  const int w = tid >> 6;

  const int gx = gridDim.x;
  const int nwg = gx * gridDim.y;
  const int id = blockIdx.y * gx + blockIdx.x;
  const int cpx = nwg >> 3;
  const int lt = (id & 7) * cpx + (id >> 3);
  const size_t m0 = (size_t)(lt / gx) * 128;
  const size_t n0 = (size_t)(lt % gx) * 128;

  const int rsub = lane >> 3;
  const int sslot = (lane & 7) ^ rsub;
  const unsigned short* Ab = A + m0 * lda + (size_t)rsub * lda + sslot * 8;
  const unsigned short* Bb = B + n0 * ldb + (size_t)rsub * ldb + sslot * 8;

  f32x4 acc[4][4] = {};

  const int fr = lane & 15;
  const int q = lane >> 4;
  const int f7 = fr & 7;

  for (int k0 = 0; k0 < K; k0 += 64) {
#pragma unroll
    for (int i = 0; i < 4; ++i) {
      const int r0 = w * 32 + i * 8;
      gl_lds16(Ab + (size_t)r0 * lda + k0, &As[r0][0]);
      gl_lds16(Bb + (size_t)r0 * ldb + k0, &Bs[r0][0]);
    }
    __syncthreads();

    bf16x8 af[4][2], bf_[4][2];
#pragma unroll
    for (int i = 0; i < 4; ++i) {
#pragma unroll
      for (int kk = 0; kk < 2; ++kk) {
        const int sA = (((kk * 4 + q) ^ f7) << 3);
        af[i][kk] = *reinterpret_cast<const bf16x8*>(
            &As[(w >> 1) * 64 + i * 16 + fr][sA]);
        bf_[i][kk] = *reinterpret_cast<const bf16x8*>(
            &Bs[(w & 1) * 64 + i * 16 + fr][sA]);
      }
    }
#pragma unroll
    for (int kk = 0; kk < 2; ++kk)
#pragma unroll
      for (int i = 0; i < 4; ++i)
#pragma unroll
        for (int j = 0; j < 4; ++j)
          acc[i][j] = __builtin_amdgcn_mfma_f32_16x16x32_bf16(
              af[i][kk], bf_[j][kk], acc[i][j], 0, 0, 0);
    __syncthreads();
  }

  const int crb = q * 4;
#pragma unroll
  for (int i = 0; i < 4; ++i) {
    size_t row = m0 + (w >> 1) * 64 + i * 16 + crb;
#pragma unroll
    for (int j = 0; j < 4; ++j) {
      size_t col = n0 + (w & 1) * 64 + j * 16 + fr;
      float bv = bias[col];
#pragma unroll
      for (int r = 0; r < 4; ++r)
        C[(row + r) * ldc + col] = f2bf(softplus_fast(acc[i][j][r] + bv));
    }
  }
}

// ---------------------------------------------------------------------------
// Skinny x_dbl GEMM: P[z][m][c] = sum_{k in z-chunk} u[m][k]*xpw[c][k].
// ---------------------------------------------------------------------------
__global__ __launch_bounds__(256) void gemm_xdbl(
    const unsigned short* __restrict__ A,  // u bf16 [4096][2048]
    const unsigned short* __restrict__ B,  // xpw bf16 [96][2048]
    float* __restrict__ P) {               // partials [4][4096][96]
  __shared__ __align__(16) unsigned short As[128][64];
  __shared__ __align__(16) unsigned short Bs[96][64];

  const int tid = threadIdx.x;
  const int lane = tid & 63;
  const int w = tid >> 6;
  const size_t m0 = (size_t)blockIdx.x * 128;
  const int k0base = blockIdx.y * 512;

  const int rsub = lane >> 3;
  const int sslot = (lane & 7) ^ rsub;
  const unsigned short* Ab = A + m0 * DI + (size_t)rsub * DI + sslot * 8;
  const unsigned short* Bb = B + (size_t)rsub * DI + sslot * 8;

  f32x4 acc[4][3] = {};

  const int fr = lane & 15;
  const int q = lane >> 4;
  const int f7 = fr & 7;

  for (int ks = 0; ks < 8; ++ks) {
    const int k0 = k0base + ks * 64;
#pragma unroll
    for (int i = 0; i < 4; ++i) {
      const int r0 = w * 32 + i * 8;
      gl_lds16(Ab + (size_t)r0 * DI + k0, &As[r0][0]);
    }
#pragma unroll
    for (int i = 0; i < 3; ++i) {
      const int r0 = w * 24 + i * 8;
      gl_lds16(Bb + (size_t)r0 * DI + k0, &Bs[r0][0]);
    }
    __syncthreads();

    bf16x8 af[4][2], bf_[3][2];
#pragma unroll
    for (int kk = 0; kk < 2; ++kk) {
      const int sA = (((kk * 4 + q) ^ f7) << 3);
#pragma unroll
      for (int i = 0; i < 4; ++i)
        af[i][kk] = *reinterpret_cast<const bf16x8*>(
            &As[(w >> 1) * 64 + i * 16 + fr][sA]);
#pragma unroll
      for (int j = 0; j < 3; ++j)
        bf_[j][kk] = *reinterpret_cast<const bf16x8*>(
            &Bs[(w & 1) * 48 + j * 16 + fr][sA]);
    }
#pragma unroll
    for (int kk = 0; kk < 2; ++kk)
#pragma unroll
      for (int i = 0; i < 4; ++i)
#pragma unroll
        for (int j = 0; j < 3; ++j)
          acc[i][j] = __builtin_amdgcn_mfma_f32_16x16x32_bf16(
              af[i][kk], bf_[j][kk], acc[i][j], 0, 0, 0);
    __syncthreads();
  }

  float* Pz = P + (size_t)blockIdx.y * PN;
  const int crb = q * 4;
#pragma unroll
  for (int i = 0; i < 4; ++i) {
    size_t row = m0 + (w >> 1) * 64 + i * 16 + crb;
#pragma unroll
    for (int j = 0; j < 3; ++j) {
      int col = (w & 1) * 48 + j * 16 + fr;
#pragma unroll
      for (int r = 0; r < 4; ++r) Pz[(row + r) * XDR + col] = acc[i][j][r];
    }
  }
}

// reduce split-K partials; emit dt as bf16 (cols 0..63) and compact B/C f32.
__global__ __launch_bounds__(256) void reduce4x_kernel(
    const float* __restrict__ P, unsigned short* __restrict__ dtB,
    float* __restrict__ BC) {
  int i = blockIdx.x * 256 + threadIdx.x;  // < 4096*96
  int row = i / XDR, col = i - row * XDR;
  float s = (P[i] + P[PN + i]) + (P[2 * PN + i] + P[3 * PN + i]);
  if (col < 64)
    dtB[row * 64 + col] = f2bf(s);
  else
    BC[row * 32 + (col - 64)] = s;
}

// ---------------------------------------------------------------------------
// Depthwise causal conv (D_CONV=4) + bias + SiLU; f32 in, bf16 out.
// ---------------------------------------------------------------------------
__global__ __launch_bounds__(256) void conv_silu_kernel(
    const float* __restrict__ x, const float* __restrict__ w,
    const float* __restrict__ cb, unsigned short* __restrict__ out) {
  int idx = blockIdx.x * 256 + threadIdx.x;
  int e4 = idx % (DI / 4);
  int bl = idx / (DI / 4);
  int l = bl % LSEQ;
  int e = e4 * 4;

  const float4* cw = reinterpret_cast<const float4*>(w);
  float4 w0 = cw[e], w1 = cw[e + 1], w2 = cw[e + 2], w3 = cw[e + 3];
  float4 acc = *reinterpret_cast<const float4*>(&cb[e]);

#define TAPK(K, COMP)                                                       \
  {                                                                         \
    int ls = l - 3 + (K);                                                   \
    if (ls >= 0) {                                                          \
      float4 xv = *reinterpret_cast<const float4*>(                         \
          &x[((size_t)(bl) - 3 + (K)) * DI + e]);                           \
      acc.x = fmaf(xv.x, w0.COMP, acc.x);                                   \
      acc.y = fmaf(xv.y, w1.COMP, acc.y);                                   \
      acc.z = fmaf(xv.z, w2.COMP, acc.z);                                   \
      acc.w = fmaf(xv.w, w3.COMP, acc.w);                                   \
    }                                                                       \
  }
  TAPK(0, x)
  TAPK(1, y)
  TAPK(2, z)
  TAPK(3, w)
#undef TAPK

  acc.x = acc.x / (1.f + expf(-acc.x));
  acc.y = acc.y / (1.f + expf(-acc.y));
  acc.z = acc.z / (1.f + expf(-acc.z));
  acc.w = acc.w / (1.f + expf(-acc.w));
  *reinterpret_cast<uint2*>(&out[(size_t)bl * DI + e]) =
      make_uint2(pack2(acc.x, acc.y), pack2(acc.z, acc.w));
}

// ---------------------------------------------------------------------------
// Chunked selective scan, 16 states/thread, 8-step load batches with
// 2-batch (16-step) lookahead to hide the 4KB-strided load latency.
// Double-buffered via statically-named register arrays (all indices are
// compile-time constants inside #pragma unroll -> stays in VGPRs).
// ---------------------------------------------------------------------------
__global__ __launch_bounds__(256) void scan_passA(
    const unsigned short* __restrict__ dB, const unsigned short* __restrict__ u,
    const float* __restrict__ bc, const float* __restrict__ A_log,
    float* __restrict__ sEnd, float* __restrict__ sProd) {
  int g = blockIdx.x * 256 + threadIdx.x;  // B*E*NC = 262144
  int e = g & (DI - 1);
  int c = (g >> 11) & (NC - 1);
  int b = g >> 17;

  const float nA0 = -__expf(A_log[e * DSTATE]);
  bool aok = true;
#pragma unroll
  for (int n = 1; n < DSTATE; ++n) {
    float nAn = -__expf(A_log[e * DSTATE + n]);
    aok = aok && (fabsf(nAn - (float)(n + 1) * nA0) <= 1e-4f * fabsf(nAn));
  }

  const size_t off0 = ((size_t)b * LSEQ + c * TC) * DI + e;
  const size_t boff0 = ((size_t)b * LSEQ + c * TC) * 32;

  float s[DSTATE], P[DSTATE];
#pragma unroll
  for (int n = 0; n < DSTATE; ++n) { s[n] = 0.f; P[n] = 1.f; }

  unsigned short dXa[8], uXa[8], dXb[8], uXb[8];

#define LOADA(DD, UU, T0)                                                   \
  {                                                                         \
    _Pragma("unroll") for (int tt = 0; tt < 8; ++tt) {                      \
      size_t o_ = off0 + (size_t)((T0) + tt) * DI;                          \
      DD[tt] = dB[o_];                                                      \
      UU[tt] = u[o_];                                                       \
    }                                                                       \
  }

#define STEPA(DD, UU, T0)                                                   \
  {                                                                         \
    _Pragma("unroll") for (int tt = 0; tt < 8; ++tt) {                      \
      float d_v = bf2f(DD[tt]);                                             \
      float u_v = bf2f(UU[tt]);                                             \
      float db_v = d_v * u_v;                                               \
      float dA[DSTATE];                                                     \
      if (aok) {                                                            \
        pow_tree(__expf(d_v * nA0), dA);                                    \
      } else {                                                              \
        _Pragma("unroll") for (int n = 0; n < DSTATE; ++n)                  \
            dA[n] = __expf(-d_v * __expf(A_log[e * DSTATE + n]));           \
      }                                                                     \
      const float4* bcp = reinterpret_cast<const float4*>(                  \
          &bc[boff0 + (size_t)((T0) + tt) * 32]);                           \
      float4 B0 = bcp[0], B1 = bcp[1], B2 = bcp[2], B3 = bcp[3];            \
      float Bv[DSTATE] = {B0.x, B0.y, B0.z, B0.w, B1.x, B1.y, B1.z, B1.w,   \
                          B2.x, B2.y, B2.z, B2.w, B3.x, B3.y, B3.z, B3.w};  \
      _Pragma("unroll") for (int n = 0; n < DSTATE; ++n) {                  \
        s[n] = fmaf(s[n], dA[n], db_v * Bv[n]);                             \
        P[n] *= dA[n];                                                      \
      }                                                                     \
    }                                                                       \
  }

  LOADA(dXa, uXa, 0);
  LOADA(dXb, uXb, 8);
  STEPA(dXa, uXa, 0);
  LOADA(dXa, uXa, 16);
  STEPA(dXb, uXb, 8);
  LOADA(dXb, uXb, 24);
  STEPA(dXa, uXa, 16);
  STEPA(dXb, uXb, 24);
#undef LOADA
#undef STEPA

  size_t o = (((size_t)b * NC + c) * DI + e) * DSTATE;
  float4* se = reinterpret_cast<float4*>(&sEnd[o]);
  float4* sp = reinterpret_cast<float4*>(&sProd[o]);
  se[0] = make_float4(s[0], s[1], s[2], s[3]);
  se[1] = make_float4(s[4], s[5], s[6], s[7]);
  se[2] = make_float4(s[8], s[9], s[10], s[11]);
  se[3] = make_float4(s[12], s[13], s[14], s[15]);
  sp[0] = make_float4(P[0], P[1], P[2], P[3]);
  sp[1] = make_float4(P[4], P[5], P[6], P[7]);
  sp[2] = make_float4(P[8], P[9], P[10], P[11]);
  sp[3] = make_float4(P[12], P[13], P[14], P[15]);
}

// In-place: sEnd[o] is replaced by the chunk's INITIAL state.
__global__ __launch_bounds__(256) void scan_passB(
    float* __restrict__ sEnd, const float* __restrict__ sProd) {
  int g = blockIdx.x * 256 + threadIdx.x;  // 65,536
  int n = g & 15;
  int e = (g >> 4) & (DI - 1);
  int b = g >> 15;
  float s = 0.f;
  for (int c = 0; c < NC; ++c) {
    size_t o = (((size_t)b * NC + c) * DI + e) * DSTATE + n;
    float se = sEnd[o];
    float sp = sProd[o];
    sEnd[o] = s;
    s = fmaf(s, sp, se);
  }
}

__global__ __launch_bounds__(256) void scan_passC(
    const unsigned short* __restrict__ dB, const unsigned short* __restrict__ u,
    const unsigned short* __restrict__ z, const float* __restrict__ bc,
    const float* __restrict__ A_log, const float* __restrict__ Dv,
    const float* __restrict__ sInit, unsigned short* __restrict__ gOut) {
  int g = blockIdx.x * 256 + threadIdx.x;  // 262144
  int e = g & (DI - 1);
  int c = (g >> 11) & (NC - 1);
  int b = g >> 17;

  const float nA0 = -__expf(A_log[e * DSTATE]);
  bool aok = true;
#pragma unroll
  for (int n = 1; n < DSTATE; ++n) {
    float nAn = -__expf(A_log[e * DSTATE + n]);
    aok = aok && (fabsf(nAn - (float)(n + 1) * nA0) <= 1e-4f * fabsf(nAn));
  }
  const float Dval = Dv[e];

  const size_t off0 = ((size_t)b * LSEQ + c * TC) * DI + e;
  const size_t boff0 = ((size_t)b * LSEQ + c * TC) * 32;

  float s[DSTATE];
  {
    size_t o = (((size_t)b * NC + c) * DI + e) * DSTATE;
    const float4* si = reinterpret_cast<const float4*>(&sInit[o]);
    float4 s0 = si[0], s1 = si[1], s2 = si[2], s3 = si[3];
    s[0] = s0.x; s[1] = s0.y; s[2] = s0.z; s[3] = s0.w;
    s[4] = s1.x; s[5] = s1.y; s[6] = s1.z; s[7] = s1.w;
    s[8] = s2.x; s[9] = s2.y; s[10] = s2.z; s[11] = s2.w;
    s[12] = s3.x; s[13] = s3.y; s[14] = s3.z; s[15] = s3.w;
  }

  unsigned short dXa[8], uXa[8], zXa[8], dXb[8], uXb[8], zXb[8];

#define LOADC(DD, UU, ZZ, T0)                                               \
  {                                                                         \
    _Pragma("unroll") for (int tt = 0; tt < 8; ++tt) {                      \
      size_t o_ = off0 + (size_t)((T0) + tt) * DI;                          \
      DD[tt] = dB[o_];                                                      \
      UU[tt] = u[o_];                                                       \
      ZZ[tt] = z[o_];                                                       \
    }                                                                       \
  }

#define STEPC(DD, UU, ZZ, T0)                                               \
  {                                                                         \
    _Pragma("unroll") for (int tt = 0; tt < 8; ++tt) {                      \
      float d_v = bf2f(DD[tt]);                                             \
      float u_v = bf2f(UU[tt]);                                             \
      float z_v = bf2f(ZZ[tt]);                                             \
      float db_v = d_v * u_v;                                               \
      float dA[DSTATE];                                                     \
      if (aok) {                                                            \
        pow_tree(__expf(d_v * nA0), dA);                                    \
      } else {                                                              \
        _Pragma("unroll") for (int n = 0; n < DSTATE; ++n)                  \
            dA[n] = __expf(-d_v * __expf(A_log[e * DSTATE + n]));           \
      }                                                                     \
      const float4* bcp = reinterpret_cast<const float4*>(                  \
          &bc[boff0 + (size_t)((T0) + tt) * 32]);                           \
      float4 B0 = bcp[0], B1 = bcp[1], B2 = bcp[2], B3 = bcp[3];            \
      float4 C0 = bcp[4], C1 = bcp[5], C2 = bcp[6], C3 = bcp[7];            \
      float Bv[DSTATE] = {B0.x, B0.y, B0.z, B0.w, B1.x, B1.y, B1.z, B1.w,   \
                          B2.x, B2.y, B2.z, B2.w, B3.x, B3.y, B3.z, B3.w};  \
      float Cv[DSTATE] = {C0.x, C0.y, C0.z, C0.w, C1.x, C1.y, C1.z, C1.w,   \
                          C2.x, C2.y, C2.z, C2.w, C3.x, C3.y, C3.z, C3.w};  \
      float y0 = 0.f, y1 = 0.f, y2 = 0.f, y3 = 0.f;                         \
      _Pragma("unroll") for (int n = 0; n < 4; ++n) {                       \
        s[n] = fmaf(s[n], dA[n], db_v * Bv[n]);                             \
        y0 = fmaf(s[n], Cv[n], y0);                                         \
        s[n + 4] = fmaf(s[n + 4], dA[n + 4], db_v * Bv[n + 4]);             \
        y1 = fmaf(s[n + 4], Cv[n + 4], y1);                                 \
        s[n + 8] = fmaf(s[n + 8], dA[n + 8], db_v * Bv[n + 8]);             \
        y2 = fmaf(s[n + 8], Cv[n + 8], y2);                                 \
        s[n + 12] = fmaf(s[n + 12], dA[n + 12], db_v * Bv[n + 12]);         \
        y3 = fmaf(s[n + 12], Cv[n + 12], y3);                               \
      }                                                                     \
      float y = (y0 + y1) + (y2 + y3);                                      \
      float gate = z_v / (1.f + __expf(-z_v));                              \
      gOut[off0 + (size_t)((T0) + tt) * DI] =                               \
          f2bf((y + Dval * u_v) * gate);                                    \
    }                                                                       \
  }

  LOADC(dXa, uXa, zXa, 0);
  LOADC(dXb, uXb, zXb, 8);
  STEPC(dXa, uXa, zXa, 0);
  LOADC(dXa, uXa, zXa, 16);
  STEPC(dXb, uXb, zXb, 8);
  LOADC(dXb, uXb, zXb, 24);
  STEPC(dXa, uXa, zXa, 16);
  STEPC(dXb, uXb, zXb, 24);
#undef LOADC
#undef STEPC
}

// ---------------------------------------------------------------------------
extern "C" void kernel_launch(void* const* d_in, const int* in_sizes, int n_in,
                              void* d_out, int out_size, void* d_ws,
                              size_t ws_size, hipStream_t stream) {
  const float* hs = (const float*)d_in[0];
  const float* in2 = (const float*)d_in[1];
  const float* w1 = (const float*)d_in[2];
  const float* w2 = (const float*)d_in[3];
  const float* cw = (const float*)d_in[4];
  const float* cb = (const float*)d_in[5];
  const float* xpw = (const float*)d_in[6];
  const float* dtw = (const float*)d_in[7];
  const float* dtb = (const float*)d_in[8];
  const float* alog = (const float*)d_in[9];
  const float* Dv = (const float*)d_in[10];
  const float* ow = (const float*)d_in[11];
  float* out = (float*)d_out;

  const size_t BLE = (size_t)BATCH * LSEQ * DI;   // 8,388,608
  const size_t BLM = (size_t)BATCH * LSEQ * DM;   // 4,194,304
  const size_t WN = (size_t)DI * DM;              // 2,097,152
  const size_t SC = (size_t)BATCH * NC * DI * DSTATE;  // 4,194,304

  // Regions (floats):
  float* W = (float*)d_ws;
  float* bufX = W;             // BLE: x_pre f32; later dB (bf16, half region)
  float* M2 = W + BLE;         // BLE/2: hsb -> zb (bf16)
  float* M3 = M2 + BLE / 2;    // BLE/2: in2b -> ub (bf16)
  float* M4 = M3 + BLE / 2;    // BLE/2: wb1|wb2 -> xdblP|xpwB|dtB|dtwB -> bufG
  float* sEnd = M4 + BLE / 2;  // SC (holds sInit after passB)
  float* sProd = sEnd + SC;    // SC (dead after passB; owb here)
  float* BC = sProd + SC;      // 4096*32 = 131,072

  unsigned short* hsb = (unsigned short*)M2;
  unsigned short* zb = (unsigned short*)M2;
  unsigned short* in2b = (unsigned short*)M3;
  unsigned short* ub = (unsigned short*)M3;
  unsigned short* wb1 = (unsigned short*)M4;
  unsigned short* wb2 = wb1 + WN;
  float* xdblP = M4;                                        // 4*PN floats
  unsigned short* xpwB = (unsigned short*)(M4 + 4 * PN);    // 96*2048
  unsigned short* dtB = (unsigned short*)(M4 + 4 * PN + 98304 + 16);
  unsigned short* dtwB = (unsigned short*)(M4 + 4 * PN + 98304 + 131072 + 32);
  unsigned short* bufG = (unsigned short*)M4;
  unsigned short* dB = (unsigned short*)bufX;
  unsigned short* owb = (unsigned short*)sProd;

  const int M = BATCH * LSEQ;  // 4096
  dim3 blk(256);

  // 0. convert GEMM operands to bf16
  cvt_bf16_kernel<<<(int)(BLM / 8 / 256), blk, 0, stream>>>(hs, hsb,
                                                            (int)(BLM / 8));
  cvt_bf16_kernel<<<(int)(BLM / 8 / 256), blk, 0, stream>>>(in2, in2b,
                                                            (int)(BLM / 8));
  cvt_bf16_kernel<<<(int)(WN / 8 / 256), blk, 0, stream>>>(w1, wb1,
                                                           (int)(WN / 8));
  cvt_bf16_kernel<<<(int)(WN / 8 / 256), blk, 0, stream>>>(w2, wb2,
                                                           (int)(WN / 8));
  // 1. x_pre = hs @ w1^T  (f32 out)
  gemm_bf16_t<float><<<dim3(DI / 128, M / 128), blk, 0, stream>>>(
      hsb, wb1, bufX, DM, DM, DM, DI);
  // 2. z = in2 @ w2^T  (bf16 out; hsb dead)
  gemm_bf16_t<unsigned short><<<dim3(DI / 128, M / 128), blk, 0, stream>>>(
      in2b, wb2, zb, DM, DM, DM, DI);
  // 3. u = silu(conv(x_pre) + cb)  (bf16 out; in2b dead)
  conv_silu_kernel<<<(M * (DI / 4)) / 256, blk, 0, stream>>>(bufX, cw, cb, ub);
  // 3b. convert xpw, dtw (wb1/wb2 dead)
  cvt_bf16_kernel<<<96, blk, 0, stream>>>(xpw, xpwB, XDR * DI / 8);
  cvt_bf16_kernel<<<64, blk, 0, stream>>>(dtw, dtwB, DI * DTR / 8);
  // 4. x_dbl partials = u @ xpw^T (split-K x4, MFMA) + reduce
  gemm_xdbl<<<dim3(M / 128, 4), blk, 0, stream>>>(ub, xpwB, xdblP);
  reduce4x_kernel<<<(M * XDR) / 256, blk, 0, stream>>>(xdblP, dtB, BC);
  // 5. d = softplus(dt @ dtw^T + dtb)  (bf16 out into bufX region)
  gemm_delta<<<dim3(DI / 128, M / 128), blk, 0, stream>>>(
      dtB, dtwB, dtb, dB, DTR, DTR, DTR, DI);
  // 6. chunked scan; passB in-place (sEnd -> sInit); passC emits g bf16
  scan_passA<<<(BATCH * DI * NC) / 256, blk, 0, stream>>>(dB, ub, BC, alog,
                                                          sEnd, sProd);
  scan_passB<<<(BATCH * DI * DSTATE) / 256, blk, 0, stream>>>(sEnd, sProd);
  cvt_bf16_kernel<<<(int)(WN / 8 / 256), blk, 0, stream>>>(ow, owb,
                                                           (int)(WN / 8));
  scan_passC<<<(BATCH * DI * NC) / 256, blk, 0, stream>>>(
      dB, ub, zb, BC, alog, Dv, sEnd, bufG);
  // 7. out = g @ ow^T
  gemm_bf16_t<float><<<dim3(DM / 128, M / 128), blk, 0, stream>>>(
      bufG, owb, out, DI, DI, DI, DM);
}

// Round 15
// 250.757 us; speedup vs baseline: 2.9359x; 2.9359x over previous
//
#include <hip/hip_runtime.h>
#include <cstddef>
#include <cmath>
#include <type_traits>

#define BATCH 2
#define LSEQ 2048
#define DM 1024
#define DSTATE 16
#define DI 2048
#define DTR 64
#define XDR 96   // DTR + 2*DSTATE
#define NC 64    // scan chunks
#define TC 32    // timesteps per chunk (NC*TC == LSEQ)
#define PN (4096 * 96)  // per-z x_dbl partial size

using f32x4 = __attribute__((ext_vector_type(4))) float;
using bf16x8 = __attribute__((ext_vector_type(8))) short;

__device__ __forceinline__ unsigned short f2bf(float f) {
  union { float f; unsigned int u; } c; c.f = f;
  unsigned int u = c.u;
  return (unsigned short)((u + 0x7FFFu + ((u >> 16) & 1u)) >> 16);  // RNE
}
__device__ __forceinline__ float bf2f(unsigned short h) {
  union { unsigned int u; float f; } c; c.u = ((unsigned int)h) << 16;
  return c.f;
}
__device__ __forceinline__ unsigned int pack2(float a, float b) {
  return (unsigned int)f2bf(a) | ((unsigned int)f2bf(b) << 16);
}

__device__ __forceinline__ void gl_lds16(const void* g, void* l) {
  __builtin_amdgcn_global_load_lds(
      (const __attribute__((address_space(1))) void*)g,
      (__attribute__((address_space(3))) void*)l, 16, 0, 0);
}

__device__ __forceinline__ float softplus_fast(float x) {
  float ex = __expf(x);
  return (x > 20.f) ? x : __logf(1.f + ex);
}

// ---------------------------------------------------------------------------
// f32 -> bf16 conversion, 8 elems/thread (exact-size grids).
// ---------------------------------------------------------------------------
__global__ __launch_bounds__(256) void cvt_bf16_kernel(
    const float* __restrict__ s, unsigned short* __restrict__ d, int n8) {
  int i = blockIdx.x * 256 + threadIdx.x;
  if (i >= n8) return;
  const float4* sp = reinterpret_cast<const float4*>(s) + (size_t)i * 2;
  float4 a = sp[0], b = sp[1];
  uint4 v = make_uint4(pack2(a.x, a.y), pack2(a.z, a.w), pack2(b.x, b.y),
                       pack2(b.z, b.w));
  *(reinterpret_cast<uint4*>(d) + i) = v;
}

// ---------------------------------------------------------------------------
// NT GEMM, bf16 in, f32 or bf16 out.  BM=BN=128, BK=64, 4 waves (2x2).
// global_load_lds staging, pre-swizzled source slots + matching XOR on
// ds_read.  XCD-aware bijective block swizzle (requires nwg % 8 == 0).
// ---------------------------------------------------------------------------
template <typename OutT>
__global__ __launch_bounds__(256) void gemm_bf16_t(
    const unsigned short* __restrict__ A, const unsigned short* __restrict__ B,
    OutT* __restrict__ C, int K, int lda, int ldb, int ldc) {
  __shared__ __align__(16) unsigned short As[128][64];
  __shared__ __align__(16) unsigned short Bs[128][64];

  const int tid = threadIdx.x;
  const int lane = tid & 63;
  const int w = tid >> 6;

  const int gx = gridDim.x;
  const int nwg = gx * gridDim.y;
  const int id = blockIdx.y * gx + blockIdx.x;
  const int cpx = nwg >> 3;
  const int lt = (id & 7) * cpx + (id >> 3);
  const size_t m0 = (size_t)(lt / gx) * 128;
  const size_t n0 = (size_t)(lt % gx) * 128;

  const int rsub = lane >> 3;
  const int sslot = (lane & 7) ^ rsub;
  const unsigned short* Ab = A + m0 * lda + (size_t)rsub * lda + sslot * 8;
  const unsigned short* Bb = B + n0 * ldb + (size_t)rsub * ldb + sslot * 8;

  f32x4 acc[4][4] = {};

  const int fr = lane & 15;
  const int q = lane >> 4;
  const int f7 = fr & 7;

  for (int k0 = 0; k0 < K; k0 += 64) {
#pragma unroll
    for (int i = 0; i < 4; ++i) {
      const int r0 = w * 32 + i * 8;
      gl_lds16(Ab + (size_t)r0 * lda + k0, &As[r0][0]);
      gl_lds16(Bb + (size_t)r0 * ldb + k0, &Bs[r0][0]);
    }
    __syncthreads();

    bf16x8 af[4][2], bf_[4][2];
#pragma unroll
    for (int i = 0; i < 4; ++i) {
#pragma unroll
      for (int kk = 0; kk < 2; ++kk) {
        const int sA = (((kk * 4 + q) ^ f7) << 3);
        af[i][kk] = *reinterpret_cast<const bf16x8*>(
            &As[(w >> 1) * 64 + i * 16 + fr][sA]);
        bf_[i][kk] = *reinterpret_cast<const bf16x8*>(
            &Bs[(w & 1) * 64 + i * 16 + fr][sA]);
      }
    }
#pragma unroll
    for (int kk = 0; kk < 2; ++kk)
#pragma unroll
      for (int i = 0; i < 4; ++i)
#pragma unroll
        for (int j = 0; j < 4; ++j)
          acc[i][j] = __builtin_amdgcn_mfma_f32_16x16x32_bf16(
              af[i][kk], bf_[j][kk], acc[i][j], 0, 0, 0);
    __syncthreads();
  }

  const int crb = q * 4;
#pragma unroll
  for (int i = 0; i < 4; ++i) {
    size_t row = m0 + (w >> 1) * 64 + i * 16 + crb;
#pragma unroll
    for (int j = 0; j < 4; ++j) {
      size_t col = n0 + (w & 1) * 64 + j * 16 + fr;
#pragma unroll
      for (int r = 0; r < 4; ++r) {
        if constexpr (std::is_same_v<OutT, unsigned short>)
          C[(row + r) * ldc + col] = f2bf(acc[i][j][r]);
        else
          C[(row + r) * ldc + col] = acc[i][j][r];
      }
    }
  }
}

// ---------------------------------------------------------------------------
// Delta GEMM with fused bias+softplus epilogue, bf16 out.
// ---------------------------------------------------------------------------
__global__ __launch_bounds__(256) void gemm_delta(
    const unsigned short* __restrict__ A, const unsigned short* __restrict__ B,
    const float* __restrict__ bias, unsigned short* __restrict__ C, int K,
    int lda, int ldb, int ldc) {
  __shared__ __align__(16) unsigned short As[128][64];
  __shared__ __align__(16) unsigned short Bs[128][64];

  const int tid = threadIdx.x;
  const int lane = tid & 63;
  const int w = tid >> 6;

  const int gx = gridDim.x;
  const int nwg = gx * gridDim.y;
  const int id = blockIdx.y * gx + blockIdx.x;
  const int cpx = nwg >> 3;
  const int lt = (id & 7) * cpx + (id >> 3);
  const size_t m0 = (size_t)(lt / gx) * 128;
  const size_t n0 = (size_t)(lt % gx) * 128;

  const int rsub = lane >> 3;
  const int sslot = (lane & 7) ^ rsub;
  const unsigned short* Ab = A + m0 * lda + (size_t)rsub * lda + sslot * 8;
  const unsigned short* Bb = B + n0 * ldb + (size_t)rsub * ldb + sslot * 8;

  f32x4 acc[4][4] = {};

  const int fr = lane & 15;
  const int q = lane >> 4;
  const int f7 = fr & 7;

  for (int k0 = 0; k0 < K; k0 += 64) {
#pragma unroll
    for (int i = 0; i < 4; ++i) {
      const int r0 = w * 32 + i * 8;
      gl_lds16(Ab + (size_t)r0 * lda + k0, &As[r0][0]);
      gl_lds16(Bb + (size_t)r0 * ldb + k0, &Bs[r0][0]);
    }
    __syncthreads();

    bf16x8 af[4][2], bf_[4][2];
#pragma unroll
    for (int i = 0; i < 4; ++i) {
#pragma unroll
      for (int kk = 0; kk < 2; ++kk) {
        const int sA = (((kk * 4 + q) ^ f7) << 3);
        af[i][kk] = *reinterpret_cast<const bf16x8*>(
            &As[(w >> 1) * 64 + i * 16 + fr][sA]);
        bf_[i][kk] = *reinterpret_cast<const bf16x8*>(
            &Bs[(w & 1) * 64 + i * 16 + fr][sA]);
      }
    }
#pragma unroll
    for (int kk = 0; kk < 2; ++kk)
#pragma unroll
      for (int i = 0; i < 4; ++i)
#pragma unroll
        for (int j = 0; j < 4; ++j)
          acc[i][j] = __builtin_amdgcn_mfma_f32_16x16x32_bf16(
              af[i][kk], bf_[j][kk], acc[i][j], 0, 0, 0);
    __syncthreads();
  }

  const int crb = q * 4;
#pragma unroll
  for (int i = 0; i < 4; ++i) {
    size_t row = m0 + (w >> 1) * 64 + i * 16 + crb;
#pragma unroll
    for (int j = 0; j < 4; ++j) {
      size_t col = n0 + (w & 1) * 64 + j * 16 + fr;
      float bv = bias[col];
#pragma unroll
      for (int r = 0; r < 4; ++r)
        C[(row + r) * ldc + col] = f2bf(softplus_fast(acc[i][j][r] + bv));
    }
  }
}

// ---------------------------------------------------------------------------
// Skinny x_dbl GEMM: P[z][m][c] = sum_{k in z-chunk} u[m][k]*xpw[c][k].
// ---------------------------------------------------------------------------
__global__ __launch_bounds__(256) void gemm_xdbl(
    const unsigned short* __restrict__ A,  // u bf16 [4096][2048]
    const unsigned short* __restrict__ B,  // xpw bf16 [96][2048]
    float* __restrict__ P) {               // partials [4][4096][96]
  __shared__ __align__(16) unsigned short As[128][64];
  __shared__ __align__(16) unsigned short Bs[96][64];

  const int tid = threadIdx.x;
  const int lane = tid & 63;
  const int w = tid >> 6;
  const size_t m0 = (size_t)blockIdx.x * 128;
  const int k0base = blockIdx.y * 512;

  const int rsub = lane >> 3;
  const int sslot = (lane & 7) ^ rsub;
  const unsigned short* Ab = A + m0 * DI + (size_t)rsub * DI + sslot * 8;
  const unsigned short* Bb = B + (size_t)rsub * DI + sslot * 8;

  f32x4 acc[4][3] = {};

  const int fr = lane & 15;
  const int q = lane >> 4;
  const int f7 = fr & 7;

  for (int ks = 0; ks < 8; ++ks) {
    const int k0 = k0base + ks * 64;
#pragma unroll
    for (int i = 0; i < 4; ++i) {
      const int r0 = w * 32 + i * 8;
      gl_lds16(Ab + (size_t)r0 * DI + k0, &As[r0][0]);
    }
#pragma unroll
    for (int i = 0; i < 3; ++i) {
      const int r0 = w * 24 + i * 8;
      gl_lds16(Bb + (size_t)r0 * DI + k0, &Bs[r0][0]);
    }
    __syncthreads();

    bf16x8 af[4][2], bf_[3][2];
#pragma unroll
    for (int kk = 0; kk < 2; ++kk) {
      const int sA = (((kk * 4 + q) ^ f7) << 3);
#pragma unroll
      for (int i = 0; i < 4; ++i)
        af[i][kk] = *reinterpret_cast<const bf16x8*>(
            &As[(w >> 1) * 64 + i * 16 + fr][sA]);
#pragma unroll
      for (int j = 0; j < 3; ++j)
        bf_[j][kk] = *reinterpret_cast<const bf16x8*>(
            &Bs[(w & 1) * 48 + j * 16 + fr][sA]);
    }
#pragma unroll
    for (int kk = 0; kk < 2; ++kk)
#pragma unroll
      for (int i = 0; i < 4; ++i)
#pragma unroll
        for (int j = 0; j < 3; ++j)
          acc[i][j] = __builtin_amdgcn_mfma_f32_16x16x32_bf16(
              af[i][kk], bf_[j][kk], acc[i][j], 0, 0, 0);
    __syncthreads();
  }

  float* Pz = P + (size_t)blockIdx.y * PN;
  const int crb = q * 4;
#pragma unroll
  for (int i = 0; i < 4; ++i) {
    size_t row = m0 + (w >> 1) * 64 + i * 16 + crb;
#pragma unroll
    for (int j = 0; j < 3; ++j) {
      int col = (w & 1) * 48 + j * 16 + fr;
#pragma unroll
      for (int r = 0; r < 4; ++r) Pz[(row + r) * XDR + col] = acc[i][j][r];
    }
  }
}

// reduce split-K partials; emit dt as bf16 (cols 0..63) and compact B/C f32.
__global__ __launch_bounds__(256) void reduce4x_kernel(
    const float* __restrict__ P, unsigned short* __restrict__ dtB,
    float* __restrict__ BC) {
  int i = blockIdx.x * 256 + threadIdx.x;  // < 4096*96
  int row = i / XDR, col = i - row * XDR;
  float s = (P[i] + P[PN + i]) + (P[2 * PN + i] + P[3 * PN + i]);
  if (col < 64)
    dtB[row * 64 + col] = f2bf(s);
  else
    BC[row * 32 + (col - 64)] = s;
}

// ---------------------------------------------------------------------------
// Depthwise causal conv (D_CONV=4) + bias + SiLU; f32 in, bf16 out.
// ---------------------------------------------------------------------------
__global__ __launch_bounds__(256) void conv_silu_kernel(
    const float* __restrict__ x, const float* __restrict__ w,
    const float* __restrict__ cb, unsigned short* __restrict__ out) {
  int idx = blockIdx.x * 256 + threadIdx.x;
  int e4 = idx % (DI / 4);
  int bl = idx / (DI / 4);
  int l = bl % LSEQ;
  int e = e4 * 4;

  const float4* cw = reinterpret_cast<const float4*>(w);
  float4 w0 = cw[e], w1 = cw[e + 1], w2 = cw[e + 2], w3 = cw[e + 3];
  float4 acc = *reinterpret_cast<const float4*>(&cb[e]);

#define TAPK(K, COMP)                                                       \
  {                                                                         \
    int ls = l - 3 + (K);                                                   \
    if (ls >= 0) {                                                          \
      float4 xv = *reinterpret_cast<const float4*>(                         \
          &x[((size_t)(bl) - 3 + (K)) * DI + e]);                           \
      acc.x = fmaf(xv.x, w0.COMP, acc.x);                                   \
      acc.y = fmaf(xv.y, w1.COMP, acc.y);                                   \
      acc.z = fmaf(xv.z, w2.COMP, acc.z);                                   \
      acc.w = fmaf(xv.w, w3.COMP, acc.w);                                   \
    }                                                                       \
  }
  TAPK(0, x)
  TAPK(1, y)
  TAPK(2, z)
  TAPK(3, w)
#undef TAPK

  acc.x = acc.x / (1.f + expf(-acc.x));
  acc.y = acc.y / (1.f + expf(-acc.y));
  acc.z = acc.z / (1.f + expf(-acc.z));
  acc.w = acc.w / (1.f + expf(-acc.w));
  *reinterpret_cast<uint2*>(&out[(size_t)bl * DI + e]) =
      make_uint2(pack2(acc.x, acc.y), pack2(acc.z, acc.w));
}

// ---------------------------------------------------------------------------
// Chunked selective scan, 8 states/thread (2 threads per channel, h=lane&1).
// d pre-softplus'ed bf16; u,z bf16; B/C from compact [BL][32] f32 buffer.
// dA via one exp + power products when A_log matches the arange pattern
// (uniform runtime check; generic fallback).  Arithmetic is bitwise-matched
// to the 16-state version: dA[h*8+j] = q^(j+1) * (h ? q^8 : 1).
// ---------------------------------------------------------------------------
__global__ __launch_bounds__(256) void scan_passA(
    const unsigned short* __restrict__ dB, const unsigned short* __restrict__ u,
    const float* __restrict__ bc, const float* __restrict__ A_log,
    float* __restrict__ sEnd, float* __restrict__ sProd) {
  int g = blockIdx.x * 256 + threadIdx.x;  // B*E*NC*2 = 524288
  int h = g & 1;
  int e = (g >> 1) & (DI - 1);
  int c = (g >> 12) & (NC - 1);
  int b = g >> 18;

  const float nA0 = -__expf(A_log[e * DSTATE]);
  bool aok = true;
#pragma unroll
  for (int n = 1; n < DSTATE; ++n) {
    float nAn = -__expf(A_log[e * DSTATE + n]);
    aok = aok && (fabsf(nAn - (float)(n + 1) * nA0) <= 1e-4f * fabsf(nAn));
  }

  size_t off = ((size_t)b * LSEQ + c * TC) * DI + e;
  size_t boff = ((size_t)b * LSEQ + c * TC) * 32 + h * 8;

  float s[8], P[8];
#pragma unroll
  for (int j = 0; j < 8; ++j) { s[j] = 0.f; P[j] = 1.f; }

  float d = bf2f(dB[off]);
  float ut = bf2f(u[off]);

  for (int t = 0; t < TC; ++t) {
    float d_n = 0.f, ut_n = 0.f;
    if (t + 1 < TC) {
      d_n = bf2f(dB[off + DI]);
      ut_n = bf2f(u[off + DI]);
    }

    float db = d * ut;
    float dA[8];
    if (aok) {
      float q1 = __expf(d * nA0);
      float q2 = q1 * q1, q3 = q2 * q1, q4 = q2 * q2;
      float q5 = q4 * q1, q6 = q4 * q2, q7 = q4 * q3, q8 = q4 * q4;
      float base = h ? q8 : 1.0f;
      dA[0] = q1 * base; dA[1] = q2 * base; dA[2] = q3 * base;
      dA[3] = q4 * base; dA[4] = q5 * base; dA[5] = q6 * base;
      dA[6] = q7 * base; dA[7] = q8 * base;
    } else {
#pragma unroll
      for (int j = 0; j < 8; ++j)
        dA[j] = __expf(-d * __expf(A_log[e * DSTATE + h * 8 + j]));
    }
    const float4* bcp = reinterpret_cast<const float4*>(&bc[boff]);
    float4 B0 = bcp[0], B1 = bcp[1];
    float Bv[8] = {B0.x, B0.y, B0.z, B0.w, B1.x, B1.y, B1.z, B1.w};
#pragma unroll
    for (int j = 0; j < 8; ++j) {
      s[j] = fmaf(s[j], dA[j], db * Bv[j]);
      P[j] *= dA[j];
    }
    off += DI;
    boff += 32;
    d = d_n; ut = ut_n;
  }

  size_t o = (((size_t)b * NC + c) * DI + e) * DSTATE + h * 8;
  float4* se = reinterpret_cast<float4*>(&sEnd[o]);
  float4* sp = reinterpret_cast<float4*>(&sProd[o]);
  se[0] = make_float4(s[0], s[1], s[2], s[3]);
  se[1] = make_float4(s[4], s[5], s[6], s[7]);
  sp[0] = make_float4(P[0], P[1], P[2], P[3]);
  sp[1] = make_float4(P[4], P[5], P[6], P[7]);
}

// In-place: sEnd[o] is replaced by the chunk's INITIAL state.
__global__ __launch_bounds__(256) void scan_passB(
    float* __restrict__ sEnd, const float* __restrict__ sProd) {
  int g = blockIdx.x * 256 + threadIdx.x;  // 65,536
  int n = g & 15;
  int e = (g >> 4) & (DI - 1);
  int b = g >> 15;
  float s = 0.f;
  for (int c = 0; c < NC; ++c) {
    size_t o = (((size_t)b * NC + c) * DI + e) * DSTATE + n;
    float se = sEnd[o];
    float sp = sProd[o];
    sEnd[o] = s;
    s = fmaf(s, sp, se);
  }
}

__global__ __launch_bounds__(256) void scan_passC(
    const unsigned short* __restrict__ dB, const unsigned short* __restrict__ u,
    const unsigned short* __restrict__ z, const float* __restrict__ bc,
    const float* __restrict__ A_log, const float* __restrict__ Dv,
    const float* __restrict__ sInit, unsigned short* __restrict__ gOut) {
  int g = blockIdx.x * 256 + threadIdx.x;  // 524288
  int h = g & 1;
  int e = (g >> 1) & (DI - 1);
  int c = (g >> 12) & (NC - 1);
  int b = g >> 18;

  const float nA0 = -__expf(A_log[e * DSTATE]);
  bool aok = true;
#pragma unroll
  for (int n = 1; n < DSTATE; ++n) {
    float nAn = -__expf(A_log[e * DSTATE + n]);
    aok = aok && (fabsf(nAn - (float)(n + 1) * nA0) <= 1e-4f * fabsf(nAn));
  }
  const float Dval = Dv[e];

  size_t off = ((size_t)b * LSEQ + c * TC) * DI + e;
  size_t boff = ((size_t)b * LSEQ + c * TC) * 32 + h * 8;

  float s[8];
  {
    size_t o = (((size_t)b * NC + c) * DI + e) * DSTATE + h * 8;
    const float4* si = reinterpret_cast<const float4*>(&sInit[o]);
    float4 s0 = si[0], s1 = si[1];
    s[0] = s0.x; s[1] = s0.y; s[2] = s0.z; s[3] = s0.w;
    s[4] = s1.x; s[5] = s1.y; s[6] = s1.z; s[7] = s1.w;
  }

  float d = bf2f(dB[off]);
  float ut = bf2f(u[off]);
  float zt = bf2f(z[off]);

  for (int t = 0; t < TC; ++t) {
    float d_n = 0.f, ut_n = 0.f, zt_n = 0.f;
    if (t + 1 < TC) {
      d_n = bf2f(dB[off + DI]);
      ut_n = bf2f(u[off + DI]);
      zt_n = bf2f(z[off + DI]);
    }

    float db = d * ut;
    float dA[8];
    if (aok) {
      float q1 = __expf(d * nA0);
      float q2 = q1 * q1, q3 = q2 * q1, q4 = q2 * q2;
      float q5 = q4 * q1, q6 = q4 * q2, q7 = q4 * q3, q8 = q4 * q4;
      float base = h ? q8 : 1.0f;
      dA[0] = q1 * base; dA[1] = q2 * base; dA[2] = q3 * base;
      dA[3] = q4 * base; dA[4] = q5 * base; dA[5] = q6 * base;
      dA[6] = q7 * base; dA[7] = q8 * base;
    } else {
#pragma unroll
      for (int j = 0; j < 8; ++j)
        dA[j] = __expf(-d * __expf(A_log[e * DSTATE + h * 8 + j]));
    }
    const float4* bcp = reinterpret_cast<const float4*>(&bc[boff]);
    float4 B0 = bcp[0], B1 = bcp[1];
    float4 C0 = bcp[4], C1 = bcp[5];  // +16 floats = +4 float4s
    float Bv[8] = {B0.x, B0.y, B0.z, B0.w, B1.x, B1.y, B1.z, B1.w};
    float Cv[8] = {C0.x, C0.y, C0.z, C0.w, C1.x, C1.y, C1.z, C1.w};
    float yA = 0.f, yB = 0.f;
#pragma unroll
    for (int j = 0; j < 4; ++j) {
      s[j] = fmaf(s[j], dA[j], db * Bv[j]);
      yA = fmaf(s[j], Cv[j], yA);
      s[j + 4] = fmaf(s[j + 4], dA[j + 4], db * Bv[j + 4]);
      yB = fmaf(s[j + 4], Cv[j + 4], yB);
    }
    float yh = yA + yB;
    float y = yh + __shfl_xor(yh, 1);  // pair-sum: (y0+y1)+(y2+y3)
    if (h == 0) {
      float gate = zt / (1.f + __expf(-zt));
      gOut[off] = f2bf((y + Dval * ut) * gate);
    }

    off += DI;
    boff += 32;
    d = d_n; ut = ut_n; zt = zt_n;
  }
}

// ---------------------------------------------------------------------------
extern "C" void kernel_launch(void* const* d_in, const int* in_sizes, int n_in,
                              void* d_out, int out_size, void* d_ws,
                              size_t ws_size, hipStream_t stream) {
  const float* hs = (const float*)d_in[0];
  const float* in2 = (const float*)d_in[1];
  const float* w1 = (const float*)d_in[2];
  const float* w2 = (const float*)d_in[3];
  const float* cw = (const float*)d_in[4];
  const float* cb = (const float*)d_in[5];
  const float* xpw = (const float*)d_in[6];
  const float* dtw = (const float*)d_in[7];
  const float* dtb = (const float*)d_in[8];
  const float* alog = (const float*)d_in[9];
  const float* Dv = (const float*)d_in[10];
  const float* ow = (const float*)d_in[11];
  float* out = (float*)d_out;

  const size_t BLE = (size_t)BATCH * LSEQ * DI;   // 8,388,608
  const size_t BLM = (size_t)BATCH * LSEQ * DM;   // 4,194,304
  const size_t WN = (size_t)DI * DM;              // 2,097,152
  const size_t SC = (size_t)BATCH * NC * DI * DSTATE;  // 4,194,304

  // Regions (floats):
  float* W = (float*)d_ws;
  float* bufX = W;             // BLE: x_pre f32; later dB (bf16, half region)
  float* M2 = W + BLE;         // BLE/2: hsb -> zb (bf16)
  float* M3 = M2 + BLE / 2;    // BLE/2: in2b -> ub (bf16)
  float* M4 = M3 + BLE / 2;    // BLE/2: wb1|wb2 -> xdblP|xpwB|dtB|dtwB -> bufG
  float* sEnd = M4 + BLE / 2;  // SC (holds sInit after passB)
  float* sProd = sEnd + SC;    // SC (dead after passB; owb here)
  float* BC = sProd + SC;      // 4096*32 = 131,072

  unsigned short* hsb = (unsigned short*)M2;
  unsigned short* zb = (unsigned short*)M2;
  unsigned short* in2b = (unsigned short*)M3;
  unsigned short* ub = (unsigned short*)M3;
  unsigned short* wb1 = (unsigned short*)M4;
  unsigned short* wb2 = wb1 + WN;
  float* xdblP = M4;                                        // 4*PN floats
  unsigned short* xpwB = (unsigned short*)(M4 + 4 * PN);    // 96*2048
  unsigned short* dtB = (unsigned short*)(M4 + 4 * PN + 98304 + 16);
  unsigned short* dtwB = (unsigned short*)(M4 + 4 * PN + 98304 + 131072 + 32);
  unsigned short* bufG = (unsigned short*)M4;
  unsigned short* dB = (unsigned short*)bufX;
  unsigned short* owb = (unsigned short*)sProd;

  const int M = BATCH * LSEQ;  // 4096
  dim3 blk(256);

  // 0. convert GEMM operands to bf16
  cvt_bf16_kernel<<<(int)(BLM / 8 / 256), blk, 0, stream>>>(hs, hsb,
                                                            (int)(BLM / 8));
  cvt_bf16_kernel<<<(int)(BLM / 8 / 256), blk, 0, stream>>>(in2, in2b,
                                                            (int)(BLM / 8));
  cvt_bf16_kernel<<<(int)(WN / 8 / 256), blk, 0, stream>>>(w1, wb1,
                                                           (int)(WN / 8));
  cvt_bf16_kernel<<<(int)(WN / 8 / 256), blk, 0, stream>>>(w2, wb2,
                                                           (int)(WN / 8));
  // 1. x_pre = hs @ w1^T  (f32 out)
  gemm_bf16_t<float><<<dim3(DI / 128, M / 128), blk, 0, stream>>>(
      hsb, wb1, bufX, DM, DM, DM, DI);
  // 2. z = in2 @ w2^T  (bf16 out; hsb dead)
  gemm_bf16_t<unsigned short><<<dim3(DI / 128, M / 128), blk, 0, stream>>>(
      in2b, wb2, zb, DM, DM, DM, DI);
  // 3. u = silu(conv(x_pre) + cb)  (bf16 out; in2b dead)
  conv_silu_kernel<<<(M * (DI / 4)) / 256, blk, 0, stream>>>(bufX, cw, cb, ub);
  // 3b. convert xpw, dtw (wb1/wb2 dead)
  cvt_bf16_kernel<<<96, blk, 0, stream>>>(xpw, xpwB, XDR * DI / 8);
  cvt_bf16_kernel<<<64, blk, 0, stream>>>(dtw, dtwB, DI * DTR / 8);
  // 4. x_dbl partials = u @ xpw^T (split-K x4, MFMA) + reduce
  gemm_xdbl<<<dim3(M / 128, 4), blk, 0, stream>>>(ub, xpwB, xdblP);
  reduce4x_kernel<<<(M * XDR) / 256, blk, 0, stream>>>(xdblP, dtB, BC);
  // 5. d = softplus(dt @ dtw^T + dtb)  (bf16 out into bufX region)
  gemm_delta<<<dim3(DI / 128, M / 128), blk, 0, stream>>>(
      dtB, dtwB, dtb, dB, DTR, DTR, DTR, DI);
  // 6. chunked scan; passB in-place (sEnd -> sInit); passC emits g bf16
  scan_passA<<<(BATCH * DI * NC * 2) / 256, blk, 0, stream>>>(dB, ub, BC, alog,
                                                              sEnd, sProd);
  scan_passB<<<(BATCH * DI * DSTATE) / 256, blk, 0, stream>>>(sEnd, sProd);
  cvt_bf16_kernel<<<(int)(WN / 8 / 256), blk, 0, stream>>>(ow, owb,
                                                           (int)(WN / 8));
  scan_passC<<<(BATCH * DI * NC * 2) / 256, blk, 0, stream>>>(
      dB, ub, zb, BC, alog, Dv, sEnd, bufG);
  // 7. out = g @ ow^T
  gemm_bf16_t<float><<<dim3(DM / 128, M / 128), blk, 0, stream>>>(
      bufG, owb, out, DI, DI, DI, DM);
}